// Round 1
// baseline (4277.986 us; speedup 1.0000x reference)
//
#include <hip/hip_runtime.h>
#include <math.h>

#define S_ROWS 2048
#define T_ROWS 50000
#define DIM    1024
#define KNN    4

#define TS 64
#define TT 64
#define BK 32
#define CHUNK_TILES 16
#define CHUNK_COLS  (TT * CHUNK_TILES)                          /* 1024 */
#define NUM_CHUNKS  ((T_ROWS + CHUNK_COLS - 1) / CHUNK_COLS)    /* 49   */
#define NCAND       (NUM_CHUNKS * KNN)                          /* 196  */
#define REFINE 8

// Insert (v, idx) into a sorted-descending top-N list. Strict '>' acceptance +
// strict '>' bubble means on exact ties the earlier-inserted (= lower index,
// since we scan indices ascending) entry wins — matches jax.lax.top_k.
template <int N>
__device__ __forceinline__ void insN(float v, int idx, float (&tv)[N], int (&ti)[N]) {
  if (v <= tv[N - 1]) return;
  tv[N - 1] = v; ti[N - 1] = idx;
#pragma unroll
  for (int j = N - 1; j > 0; --j) {
    if (tv[j] > tv[j - 1]) {
      float fv = tv[j]; tv[j] = tv[j - 1]; tv[j - 1] = fv;
      int   fi = ti[j]; ti[j] = ti[j - 1]; ti[j - 1] = fi;
    }
  }
}

// ---------------- Kernel 1: normalize source rows into ws ----------------
__global__ __launch_bounds__(256) void norm_src_kernel(const float* __restrict__ src,
                                                       float* __restrict__ srcn) {
  const int row = blockIdx.x;
  const int tid = threadIdx.x;
  __shared__ float red[4];
  float4 v = ((const float4*)(src + (size_t)row * DIM))[tid];
  float s = v.x * v.x + v.y * v.y + v.z * v.z + v.w * v.w;
#pragma unroll
  for (int off = 32; off; off >>= 1) s += __shfl_down(s, off, 64);
  if ((tid & 63) == 0) red[tid >> 6] = s;
  __syncthreads();
  float tot = red[0] + red[1] + red[2] + red[3];
  float r = 1.0f / fmaxf(sqrtf(tot), 1e-8f);
  float4 o; o.x = v.x * r; o.y = v.y * r; o.z = v.z * r; o.w = v.w * r;
  ((float4*)(srcn + (size_t)row * DIM))[tid] = o;
}

// ---------------- Kernel 2: target inverse norms into ws ----------------
__global__ __launch_bounds__(256) void norm_tgt_kernel(const float* __restrict__ tgt,
                                                       float* __restrict__ invn) {
  const int row = blockIdx.x;
  const int tid = threadIdx.x;
  __shared__ float red[4];
  float4 v = ((const float4*)(tgt + (size_t)row * DIM))[tid];
  float s = v.x * v.x + v.y * v.y + v.z * v.z + v.w * v.w;
#pragma unroll
  for (int off = 32; off; off >>= 1) s += __shfl_down(s, off, 64);
  if ((tid & 63) == 0) red[tid >> 6] = s;
  __syncthreads();
  if (tid == 0) {
    float tot = red[0] + red[1] + red[2] + red[3];
    invn[row] = 1.0f / fmaxf(sqrtf(tot), 1e-8f);
  }
}

// ------- Kernel 3: tiled sims GEMM with fused per-chunk running top-4 -------
// Block: 64 src rows x one 1024-col tgt chunk (16 tiles of 64). Thread r<64
// owns src row r's running top-4 across the chunk; partials go to ws.
__global__ __launch_bounds__(256) void sim_topk_kernel(const float* __restrict__ srcn,
                                                       const float* __restrict__ tgt,
                                                       const float* __restrict__ invn,
                                                       float* __restrict__ pvals,
                                                       int* __restrict__ pidx) {
  __shared__ float sA[BK][TS + 4];      // stride 68 floats: 16B-aligned rows
  __shared__ float sB[BK][TT + 4];
  __shared__ float sims[TS][TT + 1];    // stride 65: conflict-free column scan

  const int tid = threadIdx.x;
  const int tx = tid & 15;              // 4 tgt cols:  tx*4 .. tx*4+3
  const int ty = tid >> 4;              // 4 src rows:  ty*4 .. ty*4+3
  const int r0 = blockIdx.x * TS;
  const int chunk = blockIdx.y;

  float tv[KNN]; int ti[KNN];
#pragma unroll
  for (int j = 0; j < KNN; ++j) { tv[j] = -INFINITY; ti[j] = 0; }

  // staging map: each thread moves 2 float4s per matrix per K-step
  const int row0 = tid >> 3;            // 0..31
  const int row1 = row0 + 32;           // 32..63
  const int kq = tid & 7;               // which float4 of the 32-wide K slab

  for (int tile = 0; tile < CHUNK_TILES; ++tile) {
    const int c0 = chunk * CHUNK_COLS + tile * TT;
    if (c0 >= T_ROWS) break;

    const int trow0 = c0 + row0, trow1 = c0 + row1;
    const float sc0 = (trow0 < T_ROWS) ? invn[trow0] : 0.0f;
    const float sc1 = (trow1 < T_ROWS) ? invn[trow1] : 0.0f;

    float acc[4][4];
#pragma unroll
    for (int i = 0; i < 4; ++i)
#pragma unroll
      for (int j = 0; j < 4; ++j) acc[i][j] = 0.0f;

    for (int kb = 0; kb < DIM; kb += BK) {
      // ---- stage src tile (pre-normalized) transposed into LDS ----
      {
        float4 a = *(const float4*)(srcn + (size_t)(r0 + row0) * DIM + kb + kq * 4);
        sA[kq * 4 + 0][row0] = a.x; sA[kq * 4 + 1][row0] = a.y;
        sA[kq * 4 + 2][row0] = a.z; sA[kq * 4 + 3][row0] = a.w;
        float4 a2 = *(const float4*)(srcn + (size_t)(r0 + row1) * DIM + kb + kq * 4);
        sA[kq * 4 + 0][row1] = a2.x; sA[kq * 4 + 1][row1] = a2.y;
        sA[kq * 4 + 2][row1] = a2.z; sA[kq * 4 + 3][row1] = a2.w;
      }
      // ---- stage tgt tile, normalization fused via invn scale ----
      {
        float4 b = (trow0 < T_ROWS)
                       ? *(const float4*)(tgt + (size_t)trow0 * DIM + kb + kq * 4)
                       : make_float4(0.f, 0.f, 0.f, 0.f);
        sB[kq * 4 + 0][row0] = b.x * sc0; sB[kq * 4 + 1][row0] = b.y * sc0;
        sB[kq * 4 + 2][row0] = b.z * sc0; sB[kq * 4 + 3][row0] = b.w * sc0;
        float4 b2 = (trow1 < T_ROWS)
                        ? *(const float4*)(tgt + (size_t)trow1 * DIM + kb + kq * 4)
                        : make_float4(0.f, 0.f, 0.f, 0.f);
        sB[kq * 4 + 0][row1] = b2.x * sc1; sB[kq * 4 + 1][row1] = b2.y * sc1;
        sB[kq * 4 + 2][row1] = b2.z * sc1; sB[kq * 4 + 3][row1] = b2.w * sc1;
      }
      __syncthreads();
#pragma unroll
      for (int k = 0; k < BK; ++k) {
        float4 a4 = *(const float4*)&sA[k][ty * 4];
        float4 b4 = *(const float4*)&sB[k][tx * 4];
        float av[4] = {a4.x, a4.y, a4.z, a4.w};
        float bv[4] = {b4.x, b4.y, b4.z, b4.w};
#pragma unroll
        for (int i = 0; i < 4; ++i)
#pragma unroll
          for (int j = 0; j < 4; ++j) acc[i][j] = fmaf(av[i], bv[j], acc[i][j]);
      }
      __syncthreads();
    }

    // sims tile -> LDS, then row-owner threads update running top-4
#pragma unroll
    for (int i = 0; i < 4; ++i)
#pragma unroll
      for (int j = 0; j < 4; ++j) sims[ty * 4 + i][tx * 4 + j] = acc[i][j];
    __syncthreads();

    if (tid < TS) {
      for (int c = 0; c < TT; ++c) {
        int g = c0 + c;
        if (g < T_ROWS) insN<KNN>(sims[tid][c], g, tv, ti);
      }
    }
    __syncthreads();
  }

  if (tid < TS) {
    const size_t base = ((size_t)(r0 + tid) * NUM_CHUNKS + chunk) * KNN;
#pragma unroll
    for (int j = 0; j < KNN; ++j) { pvals[base + j] = tv[j]; pidx[base + j] = ti[j]; }
  }
}

// ---------------- Kernel 4: merge partials, fp64 refine, gather+average -----
__device__ __forceinline__ double blk_red_sum(double v, double* red) {
  const int tid = threadIdx.x;
#pragma unroll
  for (int off = 32; off; off >>= 1) v += __shfl_down(v, off, 64);
  __syncthreads();                       // protect red[] reuse across calls
  if ((tid & 63) == 0) red[tid >> 6] = v;
  __syncthreads();
  return red[0] + red[1] + red[2] + red[3];
}

__global__ __launch_bounds__(256) void merge_gather_kernel(
    const float* __restrict__ pvals, const int* __restrict__ pidx,
    const float* __restrict__ src, const float* __restrict__ tgt,
    float* __restrict__ out) {
  const int row = blockIdx.x;
  const int tid = threadIdx.x;
  __shared__ double red[4];
  __shared__ int cand[REFINE];
  __shared__ double cval[REFINE];
  __shared__ int fin[KNN];

  if (tid == 0) {
    float tv[REFINE]; int ti[REFINE];
#pragma unroll
    for (int j = 0; j < REFINE; ++j) { tv[j] = -INFINITY; ti[j] = 0; }
    const float* pv = pvals + (size_t)row * NCAND;
    const int* pi = pidx + (size_t)row * NCAND;
    for (int c = 0; c < NCAND; ++c) insN<REFINE>(pv[c], pi[c], tv, ti);
#pragma unroll
    for (int j = 0; j < REFINE; ++j) cand[j] = ti[j];
  }
  __syncthreads();

  // fp64 re-score of the top-8 candidates: pins selection to the true ordering
  float4 sv = ((const float4*)(src + (size_t)row * DIM))[tid];
  double ns2 = blk_red_sum((double)sv.x * sv.x + (double)sv.y * sv.y +
                           (double)sv.z * sv.z + (double)sv.w * sv.w, red);
  double sn = fmax(sqrt(ns2), 1e-8);

  for (int cc = 0; cc < REFINE; ++cc) {
    int t = cand[cc];
    float4 tv4 = ((const float4*)(tgt + (size_t)t * DIM))[tid];
    double dd = blk_red_sum((double)sv.x * tv4.x + (double)sv.y * tv4.y +
                            (double)sv.z * tv4.z + (double)sv.w * tv4.w, red);
    double tt = blk_red_sum((double)tv4.x * tv4.x + (double)tv4.y * tv4.y +
                            (double)tv4.z * tv4.z + (double)tv4.w * tv4.w, red);
    if (tid == 0) cval[cc] = dd / (sn * fmax(sqrt(tt), 1e-8));
  }
  __syncthreads();

  if (tid == 0) {
    bool used[REFINE];
#pragma unroll
    for (int j = 0; j < REFINE; ++j) used[j] = false;
    for (int k = 0; k < KNN; ++k) {
      int bj = -1; double bv = 0.0; int bidx = 0x7fffffff;
      for (int j = 0; j < REFINE; ++j) {
        if (used[j]) continue;
        if (bj < 0 || cval[j] > bv || (cval[j] == bv && cand[j] < bidx)) {
          bj = j; bv = cval[j]; bidx = cand[j];
        }
      }
      used[bj] = true;
      fin[k] = cand[bj];
    }
  }
  __syncthreads();

  const int d = tid * 4;
  float4 a = *(const float4*)(tgt + (size_t)fin[0] * DIM + d);
  float4 b = *(const float4*)(tgt + (size_t)fin[1] * DIM + d);
  float4 c = *(const float4*)(tgt + (size_t)fin[2] * DIM + d);
  float4 e = *(const float4*)(tgt + (size_t)fin[3] * DIM + d);
  float4 o;
  o.x = 0.25f * (a.x + b.x + c.x + e.x);
  o.y = 0.25f * (a.y + b.y + c.y + e.y);
  o.z = 0.25f * (a.z + b.z + c.z + e.z);
  o.w = 0.25f * (a.w + b.w + c.w + e.w);
  *(float4*)(out + (size_t)row * DIM + d) = o;
}

extern "C" void kernel_launch(void* const* d_in, const int* in_sizes, int n_in,
                              void* d_out, int out_size, void* d_ws, size_t ws_size,
                              hipStream_t stream) {
  const float* src = (const float*)d_in[0];
  const float* tgt = (const float*)d_in[1];
  float* out = (float*)d_out;

  // ws layout (~11.8 MB total)
  char* ws = (char*)d_ws;
  size_t off = 0;
  float* srcn = (float*)(ws + off); off += (size_t)S_ROWS * DIM * sizeof(float);     // 8 MB
  float* invn = (float*)(ws + off); off += ((size_t)T_ROWS * sizeof(float) + 255) & ~(size_t)255;
  float* pvals = (float*)(ws + off); off += (size_t)S_ROWS * NCAND * sizeof(float);  // 1.6 MB
  int* pidx = (int*)(ws + off); off += (size_t)S_ROWS * NCAND * sizeof(int);         // 1.6 MB

  norm_src_kernel<<<S_ROWS, 256, 0, stream>>>(src, srcn);
  norm_tgt_kernel<<<T_ROWS, 256, 0, stream>>>(tgt, invn);
  dim3 g3(S_ROWS / TS, NUM_CHUNKS);   // (32, 49); x fastest => chunk reuse in L2/LLC
  sim_topk_kernel<<<g3, 256, 0, stream>>>(srcn, tgt, invn, pvals, pidx);
  merge_gather_kernel<<<S_ROWS, 256, 0, stream>>>(pvals, pidx, src, tgt, out);
}

// Round 2
// 899.139 us; speedup vs baseline: 4.7579x; 4.7579x over previous
//
#include <hip/hip_runtime.h>
#include <math.h>

#define S_ROWS 2048
#define T_ROWS 50000
#define DIM    1024
#define KNN    4

#define BM 128
#define BN 128
#define BKK 32
#define TILES_PER_CHUNK 4
#define CHUNK_COLS (BN * TILES_PER_CHUNK)                    /* 512 */
#define NUM_CHUNKS ((T_ROWS + CHUNK_COLS - 1) / CHUNK_COLS)  /* 98  */
#define NCAND (NUM_CHUNKS * KNN)                             /* 392 */
#define REFINE 8
#define SP 67  /* sims LDS row stride (floats): write ~2-way, scan 2-way banks */

typedef unsigned int uint;
typedef unsigned short ushort;
typedef unsigned long long u64;
typedef __attribute__((ext_vector_type(8))) short short8;   // 8 bf16 (4 VGPRs)
typedef __attribute__((ext_vector_type(4))) float f32x4;

// bf16(x)|bf16(y)<<16 by truncation (bias ~2^-9 relative; selection is fixed
// by the fp64 refine, so cheap rounding is fine)
__device__ __forceinline__ uint pk2(float x, float y) {
  return (__float_as_uint(x) >> 16) | (__float_as_uint(y) & 0xFFFF0000u);
}

// order-preserving pack: key(val) in high 32, ~idx in low 32 (lower idx wins ties)
__device__ __forceinline__ u64 packvi(float v, int idx) {
  uint u = __float_as_uint(v);
  u ^= (uint)((int)u >> 31) | 0x80000000u;
  return ((u64)u << 32) | (uint)(~idx);
}

template <int N>
__device__ __forceinline__ void insU(u64 p, u64 (&tv)[N]) {
  if (p <= tv[N - 1]) return;
  tv[N - 1] = p;
#pragma unroll
  for (int j = N - 1; j > 0; --j) {
    if (tv[j] > tv[j - 1]) { u64 t = tv[j]; tv[j] = tv[j - 1]; tv[j - 1] = t; }
  }
}

// ---------------- Kernel 1: normalize source rows -> bf16 ----------------
__global__ __launch_bounds__(256) void norm_src_kernel(const float* __restrict__ src,
                                                       ushort* __restrict__ srcn) {
  const int row = blockIdx.x;
  const int tid = threadIdx.x;
  __shared__ float red[4];
  float4 v = ((const float4*)(src + ((size_t)row << 10)))[tid];
  float s = v.x * v.x + v.y * v.y + v.z * v.z + v.w * v.w;
#pragma unroll
  for (int off = 32; off; off >>= 1) s += __shfl_down(s, off, 64);
  if ((tid & 63) == 0) red[tid >> 6] = s;
  __syncthreads();
  float tot = red[0] + red[1] + red[2] + red[3];
  float r = 1.0f / fmaxf(sqrtf(tot), 1e-8f);
  uint2 o;
  o.x = pk2(v.x * r, v.y * r);
  o.y = pk2(v.z * r, v.w * r);
  ((uint2*)(srcn + ((size_t)row << 10)))[tid] = o;
}

// ---------------- Kernel 2: target inverse norms ----------------
__global__ __launch_bounds__(256) void norm_tgt_kernel(const float* __restrict__ tgt,
                                                       float* __restrict__ invn) {
  const int row = blockIdx.x;
  const int tid = threadIdx.x;
  __shared__ float red[4];
  float4 v = ((const float4*)(tgt + ((size_t)row << 10)))[tid];
  float s = v.x * v.x + v.y * v.y + v.z * v.z + v.w * v.w;
#pragma unroll
  for (int off = 32; off; off >>= 1) s += __shfl_down(s, off, 64);
  if ((tid & 63) == 0) red[tid >> 6] = s;
  __syncthreads();
  if (tid == 0) {
    float tot = red[0] + red[1] + red[2] + red[3];
    invn[row] = 1.0f / fmaxf(sqrtf(tot), 1e-8f);
  }
}

// ------- Kernel 3: bf16 MFMA sims GEMM with fused per-chunk top-4 -------
// 128x128 tile, BK=32, 4 waves each owning a 64x64 quadrant (4x4 MFMA 16x16x32).
// B (target) staged fp32->scaled bf16 on the fly. Epilogue: per 128-col tile,
// two 64-col phases through LDS sims[128][67]; 256 threads scan (2 threads/row,
// 32 cols each), merged at block end; packed u64 partials per (row, chunk).
union __align__(16) SimSmem {
  ushort ab[2][BM * BKK];  // sA, sB: 8 KB each
  float sims[BM * SP];     // 34304 B (max member)
  u64 mb[256 * KNN];       // 8 KB merge buffer
};

template <int WSBIG>  // tag only: rocprof Kernel_Name reveals ws_size >= 140MB
__global__ __launch_bounds__(256) void sim_topk_kernel(
    const ushort* __restrict__ srcn, const float* __restrict__ tgt,
    const float* __restrict__ invn, u64* __restrict__ partials) {
  __shared__ SimSmem sm;
  ushort* sA = sm.ab[0];
  ushort* sB = sm.ab[1];

  const int tid = threadIdx.x;
  const int lane = tid & 63;
  const int wave = tid >> 6;
  const int qr = (wave >> 1) * 64;  // quadrant row base
  const int qch = wave & 1;         // quadrant col half (0: cols 0-63, 1: 64-127)
  const int m = lane & 15;
  const int quad = lane >> 4;

  const int r0 = blockIdx.x * BM;
  const int chunk = blockIdx.y;

  // staging map: 2 threads per row, 16 elems (32 B) each
  const int sr = tid >> 1;
  const int sh = tid & 1;
  const ushort* aptr = srcn + ((size_t)(r0 + sr) << 10) + (sh << 4);
  ushort* sAw = sA + sr * BKK + sh * 16;
  ushort* sBw = sB + sr * BKK + sh * 16;

  u64 topp[KNN] = {0, 0, 0, 0};

  for (int tile = 0; tile < TILES_PER_CHUNK; ++tile) {
    const int c0 = chunk * CHUNK_COLS + tile * BN;
    if (c0 >= T_ROWS) break;  // uniform across block

    const int tr = c0 + sr;
    const bool bvalid = tr < T_ROWS;
    const float bscale = bvalid ? invn[tr] : 0.0f;  // OOB rows read row 0, zeroed by scale
    const float* bptr = tgt + ((size_t)(bvalid ? tr : 0) << 10) + (sh << 4);

    f32x4 acc[4][4];
#pragma unroll
    for (int i = 0; i < 4; ++i)
#pragma unroll
      for (int j = 0; j < 4; ++j) acc[i][j] = (f32x4){0.f, 0.f, 0.f, 0.f};

    for (int kb = 0; kb < DIM; kb += BKK) {
      uint4 a0 = *(const uint4*)(aptr + kb);
      uint4 a1 = *(const uint4*)(aptr + kb + 8);
      const float4* bp = (const float4*)(bptr + kb);
      float4 b0 = bp[0], b1 = bp[1], b2 = bp[2], b3 = bp[3];
      uint4 w0, w1;
      w0.x = pk2(b0.x * bscale, b0.y * bscale);
      w0.y = pk2(b0.z * bscale, b0.w * bscale);
      w0.z = pk2(b1.x * bscale, b1.y * bscale);
      w0.w = pk2(b1.z * bscale, b1.w * bscale);
      w1.x = pk2(b2.x * bscale, b2.y * bscale);
      w1.y = pk2(b2.z * bscale, b2.w * bscale);
      w1.z = pk2(b3.x * bscale, b3.y * bscale);
      w1.w = pk2(b3.z * bscale, b3.w * bscale);
      *(uint4*)sAw = a0;
      *(uint4*)(sAw + 8) = a1;
      *(uint4*)sBw = w0;
      *(uint4*)(sBw + 8) = w1;
      __syncthreads();

      const ushort* abase = sA + (qr + m) * BKK + quad * 8;
      const ushort* bbase = sB + (qch * 64 + m) * BKK + quad * 8;
      short8 af[4], bfr[4];
#pragma unroll
      for (int i = 0; i < 4; ++i) af[i] = *(const short8*)(abase + i * 16 * BKK);
#pragma unroll
      for (int j = 0; j < 4; ++j) bfr[j] = *(const short8*)(bbase + j * 16 * BKK);
#pragma unroll
      for (int i = 0; i < 4; ++i)
#pragma unroll
        for (int j = 0; j < 4; ++j)
          acc[i][j] = __builtin_amdgcn_mfma_f32_16x16x32_bf16(af[i], bfr[j], acc[i][j], 0, 0, 0);
      __syncthreads();
    }

    // epilogue: C layout row=(lane>>4)*4+reg, col=lane&15 (m89-verified)
#pragma unroll
    for (int ph = 0; ph < 2; ++ph) {
      if (qch == ph) {
#pragma unroll
        for (int i = 0; i < 4; ++i)
#pragma unroll
          for (int j = 0; j < 4; ++j)
#pragma unroll
            for (int reg = 0; reg < 4; ++reg)
              sm.sims[(qr + i * 16 + quad * 4 + reg) * SP + j * 16 + m] = acc[i][j][reg];
      }
      __syncthreads();
      {
        const int rowl = tid & 127;
        const int chh = tid >> 7;  // which 32-col half of this 64-col phase
        const float* srow = &sm.sims[rowl * SP + chh * 32];
        const int gbase = c0 + ph * 64 + chh * 32;
#pragma unroll 4
        for (int c = 0; c < 32; ++c) {
          const int g = gbase + c;
          if (g < T_ROWS) insU<KNN>(packvi(srow[c], g), topp);
        }
      }
      __syncthreads();
    }
  }

  // merge the two col-half owners of each row, write chunk partials
#pragma unroll
  for (int j = 0; j < KNN; ++j) sm.mb[tid * KNN + j] = topp[j];
  __syncthreads();
  if (tid < 128) {
#pragma unroll
    for (int j = 0; j < KNN; ++j) insU<KNN>(sm.mb[(tid + 128) * KNN + j], topp);
    u64* dst = partials + ((size_t)(r0 + tid) * NUM_CHUNKS + chunk) * KNN;
#pragma unroll
    for (int j = 0; j < KNN; ++j) dst[j] = topp[j];
  }
}

// ---------------- Kernel 4: merge partials, fp64 refine, gather+average -----
__device__ __forceinline__ double blk_red_sum(double v, double* red) {
  const int tid = threadIdx.x;
#pragma unroll
  for (int off = 32; off; off >>= 1) v += __shfl_down(v, off, 64);
  __syncthreads();
  if ((tid & 63) == 0) red[tid >> 6] = v;
  __syncthreads();
  return red[0] + red[1] + red[2] + red[3];
}

__global__ __launch_bounds__(256) void merge_gather_kernel(
    const u64* __restrict__ partials, const float* __restrict__ src,
    const float* __restrict__ tgt, float* __restrict__ out) {
  const int row = blockIdx.x;
  const int tid = threadIdx.x;
  __shared__ u64 cbuf[NCAND];
  __shared__ double red[4];
  __shared__ int cand[REFINE];
  __shared__ double cval[REFINE];
  __shared__ int fin[KNN];

  for (int c = tid; c < NCAND; c += 256) cbuf[c] = partials[(size_t)row * NCAND + c];
  __syncthreads();

  if (tid == 0) {
    u64 t8[REFINE];
#pragma unroll
    for (int j = 0; j < REFINE; ++j) t8[j] = 0;
    for (int c = 0; c < NCAND; ++c) insU<REFINE>(cbuf[c], t8);
#pragma unroll
    for (int j = 0; j < REFINE; ++j) cand[j] = (int)(~(uint)t8[j]);
  }
  __syncthreads();

  // fp64 re-score of the top-8 candidates: pins selection to the true ordering
  float4 sv = ((const float4*)(src + ((size_t)row << 10)))[tid];
  double ns2 = blk_red_sum((double)sv.x * sv.x + (double)sv.y * sv.y +
                           (double)sv.z * sv.z + (double)sv.w * sv.w, red);
  double sn = fmax(sqrt(ns2), 1e-8);

  for (int cc = 0; cc < REFINE; ++cc) {
    int t = cand[cc];
    float4 tv4 = ((const float4*)(tgt + ((size_t)t << 10)))[tid];
    double dd = blk_red_sum((double)sv.x * tv4.x + (double)sv.y * tv4.y +
                            (double)sv.z * tv4.z + (double)sv.w * tv4.w, red);
    double tt = blk_red_sum((double)tv4.x * tv4.x + (double)tv4.y * tv4.y +
                            (double)tv4.z * tv4.z + (double)tv4.w * tv4.w, red);
    if (tid == 0) cval[cc] = dd / (sn * fmax(sqrt(tt), 1e-8));
  }
  __syncthreads();

  if (tid == 0) {
    bool used[REFINE];
#pragma unroll
    for (int j = 0; j < REFINE; ++j) used[j] = false;
    for (int k = 0; k < KNN; ++k) {
      int bj = -1; double bv = 0.0; int bidx = 0x7fffffff;
      for (int j = 0; j < REFINE; ++j) {
        if (used[j]) continue;
        if (bj < 0 || cval[j] > bv || (cval[j] == bv && cand[j] < bidx)) {
          bj = j; bv = cval[j]; bidx = cand[j];
        }
      }
      used[bj] = true;
      fin[k] = cand[bj];
    }
  }
  __syncthreads();

  const int d = tid * 4;
  float4 a = *(const float4*)(tgt + ((size_t)fin[0] << 10) + d);
  float4 b = *(const float4*)(tgt + ((size_t)fin[1] << 10) + d);
  float4 c = *(const float4*)(tgt + ((size_t)fin[2] << 10) + d);
  float4 e = *(const float4*)(tgt + ((size_t)fin[3] << 10) + d);
  float4 o;
  o.x = 0.25f * (a.x + b.x + c.x + e.x);
  o.y = 0.25f * (a.y + b.y + c.y + e.y);
  o.z = 0.25f * (a.z + b.z + c.z + e.z);
  o.w = 0.25f * (a.w + b.w + c.w + e.w);
  *(float4*)(out + ((size_t)row << 10) + d) = o;
}

extern "C" void kernel_launch(void* const* d_in, const int* in_sizes, int n_in,
                              void* d_out, int out_size, void* d_ws, size_t ws_size,
                              hipStream_t stream) {
  const float* src = (const float*)d_in[0];
  const float* tgt = (const float*)d_in[1];
  float* out = (float*)d_out;

  // ws layout (~10.8 MB; proven safe: R1 used 11.8 MB)
  char* ws = (char*)d_ws;
  size_t off = 0;
  ushort* srcn = (ushort*)(ws + off); off += (size_t)S_ROWS * DIM * sizeof(ushort);  // 4 MB
  float* invn = (float*)(ws + off); off += ((size_t)T_ROWS * sizeof(float) + 255) & ~(size_t)255;
  u64* partials = (u64*)(ws + off); off += (size_t)S_ROWS * NCAND * sizeof(u64);     // 6.4 MB

  norm_src_kernel<<<S_ROWS, 256, 0, stream>>>(src, srcn);
  norm_tgt_kernel<<<T_ROWS, 256, 0, stream>>>(tgt, invn);
  dim3 g3(S_ROWS / BM, NUM_CHUNKS);  // x fastest => 16 row-tiles share a tgt chunk in L2
  if (ws_size >= (size_t)140 * 1024 * 1024)
    sim_topk_kernel<1><<<g3, 256, 0, stream>>>(srcn, tgt, invn, partials);
  else
    sim_topk_kernel<0><<<g3, 256, 0, stream>>>(srcn, tgt, invn, partials);
  merge_gather_kernel<<<S_ROWS, 256, 0, stream>>>(partials, src, tgt, out);
}

// Round 3
// 848.436 us; speedup vs baseline: 5.0422x; 1.0598x over previous
//
#include <hip/hip_runtime.h>
#include <math.h>

#define S_ROWS 2048
#define T_ROWS 50000
#define DIM    1024
#define KNN    4

#define BM 128
#define BN 128
#define BKK 32
#define TILES_PER_CHUNK 4
#define CHUNK_COLS (BN * TILES_PER_CHUNK)                    /* 512   */
#define NUM_CHUNKS ((T_ROWS + CHUNK_COLS - 1) / CHUNK_COLS)  /* 98    */
#define T_PAD (NUM_CHUNKS * CHUNK_COLS)                      /* 50176 */
#define NCAND (NUM_CHUNKS * KNN)                             /* 392   */
#define REFINE 8
#define SP 67  /* sims LDS row stride (floats): 2-way banks on write and scan */

typedef unsigned int uint;
typedef unsigned short ushort;
typedef unsigned long long u64;
typedef __attribute__((ext_vector_type(8))) short short8;   // 8 bf16 (4 VGPRs)
typedef __attribute__((ext_vector_type(4))) float f32x4;

// bf16(x)|bf16(y)<<16 by truncation (selection is pinned by the fp64 refine)
__device__ __forceinline__ uint pk2(float x, float y) {
  return (__float_as_uint(x) >> 16) | (__float_as_uint(y) & 0xFFFF0000u);
}

// order-preserving pack: key(val) high 32, ~idx low 32 (lower idx wins ties)
__device__ __forceinline__ u64 packvi(float v, int idx) {
  uint u = __float_as_uint(v);
  u ^= (uint)((int)u >> 31) | 0x80000000u;
  return ((u64)u << 32) | (uint)(~idx);
}

template <int N>
__device__ __forceinline__ void insU(u64 p, u64 (&tv)[N]) {
  if (p <= tv[N - 1]) return;
  tv[N - 1] = p;
#pragma unroll
  for (int j = N - 1; j > 0; --j) {
    if (tv[j] > tv[j - 1]) { u64 t = tv[j]; tv[j] = tv[j - 1]; tv[j - 1] = t; }
  }
}

// async global->LDS, 16 B per lane (global_load_lds_dwordx4); LDS dest is
// wave-uniform base + lane*16 (m104/m108 caveat: layout must be lane-contiguous)
__device__ __forceinline__ void llds16(const void* g, void* l) {
  __builtin_amdgcn_global_load_lds(
      reinterpret_cast<__attribute__((address_space(1))) void*>(
          reinterpret_cast<uintptr_t>(g)),
      reinterpret_cast<__attribute__((address_space(3))) void*>(
          (unsigned)reinterpret_cast<uintptr_t>(l)),
      16, 0, 0);
}

// ---------------- Kernel 1: normalize source rows -> bf16 ----------------
__global__ __launch_bounds__(256) void norm_src_kernel(const float* __restrict__ src,
                                                       ushort* __restrict__ srcn) {
  const int row = blockIdx.x;
  const int tid = threadIdx.x;
  __shared__ float red[4];
  float4 v = ((const float4*)(src + ((size_t)row << 10)))[tid];
  float s = v.x * v.x + v.y * v.y + v.z * v.z + v.w * v.w;
#pragma unroll
  for (int off = 32; off; off >>= 1) s += __shfl_down(s, off, 64);
  if ((tid & 63) == 0) red[tid >> 6] = s;
  __syncthreads();
  float tot = red[0] + red[1] + red[2] + red[3];
  float r = 1.0f / fmaxf(sqrtf(tot), 1e-8f);
  uint2 o;
  o.x = pk2(v.x * r, v.y * r);
  o.y = pk2(v.z * r, v.w * r);
  ((uint2*)(srcn + ((size_t)row << 10)))[tid] = o;
}

// ------- Kernel 2a (pre path): normalize target rows -> bf16, pad to 50176 ----
__global__ __launch_bounds__(256) void conv_tgt_kernel(const float* __restrict__ tgt,
                                                       ushort* __restrict__ tgtn) {
  const int row = blockIdx.x;
  const int tid = threadIdx.x;
  if (row >= T_ROWS) {  // pad rows: zeros => sims 0, and scan guards g<T_ROWS anyway
    ((uint2*)(tgtn + ((size_t)row << 10)))[tid] = make_uint2(0u, 0u);
    return;
  }
  __shared__ float red[4];
  float4 v = ((const float4*)(tgt + ((size_t)row << 10)))[tid];
  float s = v.x * v.x + v.y * v.y + v.z * v.z + v.w * v.w;
#pragma unroll
  for (int off = 32; off; off >>= 1) s += __shfl_down(s, off, 64);
  if ((tid & 63) == 0) red[tid >> 6] = s;
  __syncthreads();
  float tot = red[0] + red[1] + red[2] + red[3];
  float r = 1.0f / fmaxf(sqrtf(tot), 1e-8f);
  uint2 o;
  o.x = pk2(v.x * r, v.y * r);
  o.y = pk2(v.z * r, v.w * r);
  ((uint2*)(tgtn + ((size_t)row << 10)))[tid] = o;
}

// ------- Kernel 2b (fly fallback): target inverse norms ----------------
__global__ __launch_bounds__(256) void norm_tgt_kernel(const float* __restrict__ tgt,
                                                       float* __restrict__ invn) {
  const int row = blockIdx.x;
  const int tid = threadIdx.x;
  __shared__ float red[4];
  float4 v = ((const float4*)(tgt + ((size_t)row << 10)))[tid];
  float s = v.x * v.x + v.y * v.y + v.z * v.z + v.w * v.w;
#pragma unroll
  for (int off = 32; off; off >>= 1) s += __shfl_down(s, off, 64);
  if ((tid & 63) == 0) red[tid >> 6] = s;
  __syncthreads();
  if (tid == 0) {
    float tot = red[0] + red[1] + red[2] + red[3];
    invn[row] = 1.0f / fmaxf(sqrtf(tot), 1e-8f);
  }
}

// ---------------- shared sim-kernel pieces ----------------
union __align__(16) SimSmem {
  ushort ab[2][BM * BKK];  // sA, sB: 8 KB each
  float sims[BM * SP];     // 34304 B (max member)
  u64 mb[256 * KNN];       // 8 KB merge buffer
};

// epilogue: C layout row=(lane>>4)*4+reg, col=lane&15 (m89-verified).
// Two 64-col phases through LDS sims; 2 threads/row scan 32 cols each.
__device__ __forceinline__ void epilogue_tile(SimSmem& sm, f32x4 (&acc)[4][4],
                                              int c0, int qr, int qch, int quad,
                                              int m, int tid, u64 (&topp)[KNN]) {
#pragma unroll
  for (int ph = 0; ph < 2; ++ph) {
    if (qch == ph) {
#pragma unroll
      for (int i = 0; i < 4; ++i)
#pragma unroll
        for (int j = 0; j < 4; ++j)
#pragma unroll
          for (int reg = 0; reg < 4; ++reg)
            sm.sims[(qr + i * 16 + quad * 4 + reg) * SP + j * 16 + m] = acc[i][j][reg];
    }
    __syncthreads();
    {
      const int rowl = tid & 127;
      const int chh = tid >> 7;  // which 32-col half of this 64-col phase
      const float* srow = &sm.sims[rowl * SP + chh * 32];
      const int gbase = c0 + ph * 64 + chh * 32;
#pragma unroll 4
      for (int c = 0; c < 32; ++c) {
        const int g = gbase + c;
        if (g < T_ROWS) insU<KNN>(packvi(srow[c], g), topp);
      }
    }
    __syncthreads();
  }
}

__device__ __forceinline__ void writeback_partials(SimSmem& sm, u64 (&topp)[KNN],
                                                   int tid, int r0, int chunk,
                                                   u64* partials) {
#pragma unroll
  for (int j = 0; j < KNN; ++j) sm.mb[tid * KNN + j] = topp[j];
  __syncthreads();
  if (tid < 128) {
#pragma unroll
    for (int j = 0; j < KNN; ++j) insU<KNN>(sm.mb[(tid + 128) * KNN + j], topp);
    u64* dst = partials + ((size_t)(r0 + tid) * NUM_CHUNKS + chunk) * KNN;
#pragma unroll
    for (int j = 0; j < KNN; ++j) dst[j] = topp[j];
  }
}

// ------- Kernel 3 (pre path): m97-style GEMM, both operands bf16 in HBM -------
// 128x128 tile, BK=32, global_load_lds dwordx4 staging, 4 waves x 4x4 MFMA.
__global__ __launch_bounds__(256) void sim_topk_pre(
    const ushort* __restrict__ srcn, const ushort* __restrict__ tgtn,
    u64* __restrict__ partials) {
  __shared__ SimSmem sm;
  ushort* sA = sm.ab[0];
  ushort* sB = sm.ab[1];

  const int tid = threadIdx.x;
  const int lane = tid & 63;
  const int wave = tid >> 6;
  const int qr = (wave >> 1) * 64;
  const int qch = wave & 1;
  const int m = lane & 15;
  const int quad = lane >> 4;
  const int r0 = blockIdx.x * BM;
  const int chunk = blockIdx.y;

  // staging: wave w covers rows [w*32, w*32+32) of each tile via 2 lds-loads;
  // lane i deposits 16 B at ldsbase + i*16 == row (w*32 + i/4), elems (i%4)*8
  const int srow = wave * 32 + (lane >> 2);
  const int scol = (lane & 3) * 8;
  ushort* aL = sA + wave * 32 * BKK;  // wave-uniform LDS bases
  ushort* bL = sB + wave * 32 * BKK;
  const ushort* ag = srcn + ((size_t)(r0 + srow) << 10) + scol;

  u64 topp[KNN] = {0, 0, 0, 0};

  for (int tile = 0; tile < TILES_PER_CHUNK; ++tile) {
    const int c0 = chunk * CHUNK_COLS + tile * BN;
    const ushort* bg = tgtn + ((size_t)(c0 + srow) << 10) + scol;

    f32x4 acc[4][4];
#pragma unroll
    for (int i = 0; i < 4; ++i)
#pragma unroll
      for (int j = 0; j < 4; ++j) acc[i][j] = (f32x4){0.f, 0.f, 0.f, 0.f};

    for (int kb = 0; kb < DIM; kb += BKK) {
      llds16(ag + kb, aL);
      llds16(ag + kb + (16 << 10), aL + 16 * BKK);
      llds16(bg + kb, bL);
      llds16(bg + kb + (16 << 10), bL + 16 * BKK);
      __syncthreads();

      const ushort* abase = sA + (qr + m) * BKK + quad * 8;
      const ushort* bbase = sB + (qch * 64 + m) * BKK + quad * 8;
      short8 af[4], bfr[4];
#pragma unroll
      for (int i = 0; i < 4; ++i) af[i] = *(const short8*)(abase + i * 16 * BKK);
#pragma unroll
      for (int j = 0; j < 4; ++j) bfr[j] = *(const short8*)(bbase + j * 16 * BKK);
#pragma unroll
      for (int i = 0; i < 4; ++i)
#pragma unroll
        for (int j = 0; j < 4; ++j)
          acc[i][j] = __builtin_amdgcn_mfma_f32_16x16x32_bf16(af[i], bfr[j], acc[i][j], 0, 0, 0);
      __syncthreads();
    }

    epilogue_tile(sm, acc, c0, qr, qch, quad, m, tid, topp);
  }

  writeback_partials(sm, topp, tid, r0, chunk, partials);
}

// ------- Kernel 3 (fly fallback): R2 structure, fp32 B converted on the fly ----
__device__ __forceinline__ void sim_fly_body(const ushort* __restrict__ srcn,
                                             const float* __restrict__ tgt,
                                             const float* __restrict__ invn,
                                             u64* __restrict__ partials) {
  __shared__ SimSmem sm;
  ushort* sA = sm.ab[0];
  ushort* sB = sm.ab[1];

  const int tid = threadIdx.x;
  const int lane = tid & 63;
  const int wave = tid >> 6;
  const int qr = (wave >> 1) * 64;
  const int qch = wave & 1;
  const int m = lane & 15;
  const int quad = lane >> 4;
  const int r0 = blockIdx.x * BM;
  const int chunk = blockIdx.y;

  const int sr = tid >> 1;
  const int sh = tid & 1;
  const ushort* aptr = srcn + ((size_t)(r0 + sr) << 10) + (sh << 4);
  ushort* sAw = sA + sr * BKK + sh * 16;
  ushort* sBw = sB + sr * BKK + sh * 16;

  u64 topp[KNN] = {0, 0, 0, 0};

  for (int tile = 0; tile < TILES_PER_CHUNK; ++tile) {
    const int c0 = chunk * CHUNK_COLS + tile * BN;
    if (c0 >= T_ROWS) break;

    const int tr = c0 + sr;
    const bool bvalid = tr < T_ROWS;
    const float bscale = bvalid ? invn[tr] : 0.0f;
    const float* bptr = tgt + ((size_t)(bvalid ? tr : 0) << 10) + (sh << 4);

    f32x4 acc[4][4];
#pragma unroll
    for (int i = 0; i < 4; ++i)
#pragma unroll
      for (int j = 0; j < 4; ++j) acc[i][j] = (f32x4){0.f, 0.f, 0.f, 0.f};

    for (int kb = 0; kb < DIM; kb += BKK) {
      uint4 a0 = *(const uint4*)(aptr + kb);
      uint4 a1 = *(const uint4*)(aptr + kb + 8);
      const float4* bp = (const float4*)(bptr + kb);
      float4 b0 = bp[0], b1 = bp[1], b2 = bp[2], b3 = bp[3];
      uint4 w0, w1;
      w0.x = pk2(b0.x * bscale, b0.y * bscale);
      w0.y = pk2(b0.z * bscale, b0.w * bscale);
      w0.z = pk2(b1.x * bscale, b1.y * bscale);
      w0.w = pk2(b1.z * bscale, b1.w * bscale);
      w1.x = pk2(b2.x * bscale, b2.y * bscale);
      w1.y = pk2(b2.z * bscale, b2.w * bscale);
      w1.z = pk2(b3.x * bscale, b3.y * bscale);
      w1.w = pk2(b3.z * bscale, b3.w * bscale);
      *(uint4*)sAw = a0;
      *(uint4*)(sAw + 8) = a1;
      *(uint4*)sBw = w0;
      *(uint4*)(sBw + 8) = w1;
      __syncthreads();

      const ushort* abase = sA + (qr + m) * BKK + quad * 8;
      const ushort* bbase = sB + (qch * 64 + m) * BKK + quad * 8;
      short8 af[4], bfr[4];
#pragma unroll
      for (int i = 0; i < 4; ++i) af[i] = *(const short8*)(abase + i * 16 * BKK);
#pragma unroll
      for (int j = 0; j < 4; ++j) bfr[j] = *(const short8*)(bbase + j * 16 * BKK);
#pragma unroll
      for (int i = 0; i < 4; ++i)
#pragma unroll
        for (int j = 0; j < 4; ++j)
          acc[i][j] = __builtin_amdgcn_mfma_f32_16x16x32_bf16(af[i], bfr[j], acc[i][j], 0, 0, 0);
      __syncthreads();
    }

    epilogue_tile(sm, acc, c0, qr, qch, quad, m, tid, topp);
  }

  writeback_partials(sm, topp, tid, r0, chunk, partials);
}

// distinct names so rocprof Kernel_Name reveals the ws_size bracket
__global__ __launch_bounds__(256) void sim_topk_fly_w64(
    const ushort* __restrict__ srcn, const float* __restrict__ tgt,
    const float* __restrict__ invn, u64* __restrict__ partials) {
  sim_fly_body(srcn, tgt, invn, partials);
}
__global__ __launch_bounds__(256) void sim_topk_fly_w32(
    const ushort* __restrict__ srcn, const float* __restrict__ tgt,
    const float* __restrict__ invn, u64* __restrict__ partials) {
  sim_fly_body(srcn, tgt, invn, partials);
}
__global__ __launch_bounds__(256) void sim_topk_fly_w16(
    const ushort* __restrict__ srcn, const float* __restrict__ tgt,
    const float* __restrict__ invn, u64* __restrict__ partials) {
  sim_fly_body(srcn, tgt, invn, partials);
}

// ---------------- Kernel 4: merge partials, fp64 refine, gather+average -----
__device__ __forceinline__ double blk_red_sum(double v, double* red) {
  const int tid = threadIdx.x;
#pragma unroll
  for (int off = 32; off; off >>= 1) v += __shfl_down(v, off, 64);
  __syncthreads();
  if ((tid & 63) == 0) red[tid >> 6] = v;
  __syncthreads();
  return red[0] + red[1] + red[2] + red[3];
}

__global__ __launch_bounds__(256) void merge_gather_kernel(
    const u64* __restrict__ partials, const float* __restrict__ src,
    const float* __restrict__ tgt, float* __restrict__ out) {
  const int row = blockIdx.x;
  const int tid = threadIdx.x;
  __shared__ u64 cbuf[NCAND];
  __shared__ double red[4];
  __shared__ int cand[REFINE];
  __shared__ double cval[REFINE];
  __shared__ int fin[KNN];

  for (int c = tid; c < NCAND; c += 256) cbuf[c] = partials[(size_t)row * NCAND + c];
  __syncthreads();

  if (tid == 0) {
    u64 t8[REFINE];
#pragma unroll
    for (int j = 0; j < REFINE; ++j) t8[j] = 0;
    for (int c = 0; c < NCAND; ++c) insU<REFINE>(cbuf[c], t8);
#pragma unroll
    for (int j = 0; j < REFINE; ++j) cand[j] = (int)(~(uint)t8[j]);
  }
  __syncthreads();

  // fp64 re-score of the top-8 candidates: pins selection to the true ordering
  float4 sv = ((const float4*)(src + ((size_t)row << 10)))[tid];
  double ns2 = blk_red_sum((double)sv.x * sv.x + (double)sv.y * sv.y +
                           (double)sv.z * sv.z + (double)sv.w * sv.w, red);
  double sn = fmax(sqrt(ns2), 1e-8);

  for (int cc = 0; cc < REFINE; ++cc) {
    int t = cand[cc];
    float4 tv4 = ((const float4*)(tgt + ((size_t)t << 10)))[tid];
    double dd = blk_red_sum((double)sv.x * tv4.x + (double)sv.y * tv4.y +
                            (double)sv.z * tv4.z + (double)sv.w * tv4.w, red);
    double tt = blk_red_sum((double)tv4.x * tv4.x + (double)tv4.y * tv4.y +
                            (double)tv4.z * tv4.z + (double)tv4.w * tv4.w, red);
    if (tid == 0) cval[cc] = dd / (sn * fmax(sqrt(tt), 1e-8));
  }
  __syncthreads();

  if (tid == 0) {
    bool used[REFINE];
#pragma unroll
    for (int j = 0; j < REFINE; ++j) used[j] = false;
    for (int k = 0; k < KNN; ++k) {
      int bj = -1; double bv = 0.0; int bidx = 0x7fffffff;
      for (int j = 0; j < REFINE; ++j) {
        if (used[j]) continue;
        if (bj < 0 || cval[j] > bv || (cval[j] == bv && cand[j] < bidx)) {
          bj = j; bv = cval[j]; bidx = cand[j];
        }
      }
      used[bj] = true;
      fin[k] = cand[bj];
    }
  }
  __syncthreads();

  const int d = tid * 4;
  float4 a = *(const float4*)(tgt + ((size_t)fin[0] << 10) + d);
  float4 b = *(const float4*)(tgt + ((size_t)fin[1] << 10) + d);
  float4 c = *(const float4*)(tgt + ((size_t)fin[2] << 10) + d);
  float4 e = *(const float4*)(tgt + ((size_t)fin[3] << 10) + d);
  float4 o;
  o.x = 0.25f * (a.x + b.x + c.x + e.x);
  o.y = 0.25f * (a.y + b.y + c.y + e.y);
  o.z = 0.25f * (a.z + b.z + c.z + e.z);
  o.w = 0.25f * (a.w + b.w + c.w + e.w);
  *(float4*)(out + ((size_t)row << 10) + d) = o;
}

extern "C" void kernel_launch(void* const* d_in, const int* in_sizes, int n_in,
                              void* d_out, int out_size, void* d_ws, size_t ws_size,
                              hipStream_t stream) {
  const float* src = (const float*)d_in[0];
  const float* tgt = (const float*)d_in[1];
  float* out = (float*)d_out;
  char* ws = (char*)d_ws;

  const size_t SRCN_B = (size_t)S_ROWS * DIM * sizeof(ushort);    // 4.19 MB
  const size_t TGTN_B = (size_t)T_PAD * DIM * sizeof(ushort);     // 102.76 MB
  const size_t PART_B = (size_t)S_ROWS * NCAND * sizeof(u64);     // 6.42 MB
  const size_t INVN_B = ((size_t)T_ROWS * sizeof(float) + 255) & ~(size_t)255;
  const size_t PRE_NEED = SRCN_B + TGTN_B + PART_B;               // 113.4 MB

  dim3 g3(S_ROWS / BM, NUM_CHUNKS);  // x fastest => row-tiles share a tgt chunk in L2
  u64* partials;

  norm_src_kernel<<<S_ROWS, 256, 0, stream>>>(src, (ushort*)ws);

  if (ws_size >= PRE_NEED) {
    ushort* srcn = (ushort*)ws;
    ushort* tgtn = (ushort*)(ws + SRCN_B);
    partials = (u64*)(ws + SRCN_B + TGTN_B);
    conv_tgt_kernel<<<T_PAD, 256, 0, stream>>>(tgt, tgtn);
    sim_topk_pre<<<g3, 256, 0, stream>>>(srcn, tgtn, partials);
  } else {
    ushort* srcn = (ushort*)ws;
    float* invn = (float*)(ws + SRCN_B);
    partials = (u64*)(ws + SRCN_B + INVN_B);
    norm_tgt_kernel<<<T_ROWS, 256, 0, stream>>>(tgt, invn);
    if (ws_size >= (size_t)64 << 20)
      sim_topk_fly_w64<<<g3, 256, 0, stream>>>(srcn, tgt, invn, partials);
    else if (ws_size >= (size_t)32 << 20)
      sim_topk_fly_w32<<<g3, 256, 0, stream>>>(srcn, tgt, invn, partials);
    else
      sim_topk_fly_w16<<<g3, 256, 0, stream>>>(srcn, tgt, invn, partials);
  }

  merge_gather_kernel<<<S_ROWS, 256, 0, stream>>>(partials, src, tgt, out);
}

// Round 4
// 814.434 us; speedup vs baseline: 5.2527x; 1.0417x over previous
//
#include <hip/hip_runtime.h>
#include <math.h>

#define S_ROWS 2048
#define T_ROWS 50000
#define DIM    1024
#define KNN    4

#define BM 128
#define BN 128
#define BKK 32
#define TILES_PER_CHUNK 4
#define CHUNK_COLS (BN * TILES_PER_CHUNK)                    /* 512   */
#define NUM_CHUNKS ((T_ROWS + CHUNK_COLS - 1) / CHUNK_COLS)  /* 98    */
#define T_PAD (NUM_CHUNKS * CHUNK_COLS)                      /* 50176 */
#define NCAND (NUM_CHUNKS * KNN)                             /* 392   */
#define REFINE 8
#define SP 67  /* sims LDS row stride (floats): 2-way banks on scan (free) */

typedef unsigned int uint;
typedef unsigned short ushort;
typedef unsigned long long u64;
typedef __attribute__((ext_vector_type(8))) short short8;   // 8 bf16 (4 VGPRs)
typedef __attribute__((ext_vector_type(4))) float f32x4;

#define PACK_NEGINF 0x007FFFFFFFFFFFFFULL  /* packvi(-inf, 0) */

// bf16(x)|bf16(y)<<16 by truncation (selection is pinned by the fp64 refine)
__device__ __forceinline__ uint pk2(float x, float y) {
  return (__float_as_uint(x) >> 16) | (__float_as_uint(y) & 0xFFFF0000u);
}

// order-preserving pack: key(val) high 32, ~idx low 32 (lower idx wins ties)
__device__ __forceinline__ u64 packvi(float v, int idx) {
  uint u = __float_as_uint(v);
  u ^= (uint)((int)u >> 31) | 0x80000000u;
  return ((u64)u << 32) | (uint)(~idx);
}

__device__ __forceinline__ float unpackf(u64 p) {
  uint u = (uint)(p >> 32);
  u = (u & 0x80000000u) ? (u ^ 0x80000000u) : ~u;
  return __uint_as_float(u);
}

template <int N>
__device__ __forceinline__ void insU(u64 p, u64 (&tv)[N]) {
  if (p <= tv[N - 1]) return;
  tv[N - 1] = p;
#pragma unroll
  for (int j = N - 1; j > 0; --j) {
    if (tv[j] > tv[j - 1]) { u64 t = tv[j]; tv[j] = tv[j - 1]; tv[j - 1] = t; }
  }
}

// async global->LDS, 16 B per lane (global_load_lds_dwordx4); LDS dest is
// wave-uniform base + lane*16 (m104/m108: layout must be lane-contiguous)
__device__ __forceinline__ void llds16(const void* g, void* l) {
  __builtin_amdgcn_global_load_lds(
      reinterpret_cast<__attribute__((address_space(1))) void*>(
          reinterpret_cast<uintptr_t>(g)),
      reinterpret_cast<__attribute__((address_space(3))) void*>(
          (unsigned)reinterpret_cast<uintptr_t>(l)),
      16, 0, 0);
}

// ---------------- Kernel 1: normalize source rows -> bf16 ----------------
__global__ __launch_bounds__(256) void norm_src_kernel(const float* __restrict__ src,
                                                       ushort* __restrict__ srcn) {
  const int row = blockIdx.x;
  const int tid = threadIdx.x;
  __shared__ float red[4];
  float4 v = ((const float4*)(src + ((size_t)row << 10)))[tid];
  float s = v.x * v.x + v.y * v.y + v.z * v.z + v.w * v.w;
#pragma unroll
  for (int off = 32; off; off >>= 1) s += __shfl_down(s, off, 64);
  if ((tid & 63) == 0) red[tid >> 6] = s;
  __syncthreads();
  float tot = red[0] + red[1] + red[2] + red[3];
  float r = 1.0f / fmaxf(sqrtf(tot), 1e-8f);
  uint2 o;
  o.x = pk2(v.x * r, v.y * r);
  o.y = pk2(v.z * r, v.w * r);
  ((uint2*)(srcn + ((size_t)row << 10)))[tid] = o;
}

// ------- Kernel 2: normalize target rows -> bf16, pad to 50176 ----
__global__ __launch_bounds__(256) void conv_tgt_kernel(const float* __restrict__ tgt,
                                                       ushort* __restrict__ tgtn) {
  const int row = blockIdx.x;
  const int tid = threadIdx.x;
  if (row >= T_ROWS) {  // pad rows: zeros => sims 0; scan guards g<T_ROWS anyway
    ((uint2*)(tgtn + ((size_t)row << 10)))[tid] = make_uint2(0u, 0u);
    return;
  }
  __shared__ float red[4];
  float4 v = ((const float4*)(tgt + ((size_t)row << 10)))[tid];
  float s = v.x * v.x + v.y * v.y + v.z * v.z + v.w * v.w;
#pragma unroll
  for (int off = 32; off; off >>= 1) s += __shfl_down(s, off, 64);
  if ((tid & 63) == 0) red[tid >> 6] = s;
  __syncthreads();
  float tot = red[0] + red[1] + red[2] + red[3];
  float r = 1.0f / fmaxf(sqrtf(tot), 1e-8f);
  uint2 o;
  o.x = pk2(v.x * r, v.y * r);
  o.y = pk2(v.z * r, v.w * r);
  ((uint2*)(tgtn + ((size_t)row << 10)))[tid] = o;
}

// ---------------- sim kernel ----------------
union __align__(16) SimSmem {
  ushort ab[2][BM * BKK];  // sA, sB: 8 KB each
  float sims[BM * SP];     // 34304 B (max member)
  u64 mb[256 * KNN];       // 8 KB merge buffer
};

// epilogue: C layout row=(lane>>4)*4+reg, col=lane&15 (m89-verified).
// Two 64-col phases through LDS sims; 2 threads/row scan 32 cols each,
// with a float4-max prefilter against the running 4th-best.
__device__ __forceinline__ void epilogue_tile(SimSmem& sm, f32x4 (&acc)[4][4],
                                              int c0, int qr, int qch, int quad,
                                              int m, int tid, u64 (&topp)[KNN],
                                              float& thr) {
#pragma unroll
  for (int ph = 0; ph < 2; ++ph) {
    if (qch == ph) {
#pragma unroll
      for (int i = 0; i < 4; ++i)
#pragma unroll
        for (int j = 0; j < 4; ++j)
#pragma unroll
          for (int reg = 0; reg < 4; ++reg)
            sm.sims[(qr + i * 16 + quad * 4 + reg) * SP + j * 16 + m] = acc[i][j][reg];
    }
    __syncthreads();
    {
      const int rowl = tid & 127;
      const int chh = tid >> 7;  // which 32-col half of this 64-col phase
      const float* srow = &sm.sims[rowl * SP + chh * 32];
      const int gbase = c0 + ph * 64 + chh * 32;
#pragma unroll
      for (int c = 0; c < 32; c += 4) {
        float a = srow[c], b = srow[c + 1], d = srow[c + 2], e = srow[c + 3];
        float mx = fmaxf(fmaxf(a, b), fmaxf(d, e));
        if (mx > thr) {  // rare: enter guarded per-element insert
          const int g = gbase + c;
          if (g + 0 < T_ROWS) insU<KNN>(packvi(a, g + 0), topp);
          if (g + 1 < T_ROWS) insU<KNN>(packvi(b, g + 1), topp);
          if (g + 2 < T_ROWS) insU<KNN>(packvi(d, g + 2), topp);
          if (g + 3 < T_ROWS) insU<KNN>(packvi(e, g + 3), topp);
          thr = unpackf(topp[KNN - 1]);
        }
      }
    }
    __syncthreads();
  }
}

__device__ __forceinline__ void writeback_partials(SimSmem& sm, u64 (&topp)[KNN],
                                                   int tid, int r0, int chunk,
                                                   u64* partials) {
#pragma unroll
  for (int j = 0; j < KNN; ++j) sm.mb[tid * KNN + j] = topp[j];
  __syncthreads();
  if (tid < 128) {
#pragma unroll
    for (int j = 0; j < KNN; ++j) insU<KNN>(sm.mb[(tid + 128) * KNN + j], topp);
    u64* dst = partials + ((size_t)(r0 + tid) * NUM_CHUNKS + chunk) * KNN;
#pragma unroll
    for (int j = 0; j < KNN; ++j) dst[j] = topp[j];
  }
}

// m97-style GEMM: 128x128 tile, BK=32, global_load_lds dwordx4 staging,
// 4 waves x 4x4 MFMA 16x16x32 bf16, fused per-chunk top-4.
__device__ __forceinline__ void sim_pre_body(const ushort* __restrict__ srcn,
                                             const ushort* __restrict__ tgtn,
                                             u64* __restrict__ partials) {
  __shared__ SimSmem sm;
  ushort* sA = sm.ab[0];
  ushort* sB = sm.ab[1];

  const int tid = threadIdx.x;
  const int lane = tid & 63;
  const int wave = tid >> 6;
  const int qr = (wave >> 1) * 64;
  const int qch = wave & 1;
  const int m = lane & 15;
  const int quad = lane >> 4;
  const int r0 = blockIdx.x * BM;
  const int chunk = blockIdx.y;

  // staging: wave w covers rows [w*32, w*32+32) of each tile via 2 lds-DMAs;
  // lane i deposits 16 B at ldsbase + i*16 == row (w*32 + i/4), elems (i%4)*8
  const int srow = wave * 32 + (lane >> 2);
  const int scol = (lane & 3) * 8;
  ushort* aL = sA + wave * 32 * BKK;  // wave-uniform LDS bases
  ushort* bL = sB + wave * 32 * BKK;
  const ushort* ag = srcn + ((size_t)(r0 + srow) << 10) + scol;

  u64 topp[KNN] = {PACK_NEGINF, PACK_NEGINF, PACK_NEGINF, PACK_NEGINF};
  float thr = -INFINITY;

  for (int tile = 0; tile < TILES_PER_CHUNK; ++tile) {
    const int c0 = chunk * CHUNK_COLS + tile * BN;
    const ushort* bg = tgtn + ((size_t)(c0 + srow) << 10) + scol;

    f32x4 acc[4][4];
#pragma unroll
    for (int i = 0; i < 4; ++i)
#pragma unroll
      for (int j = 0; j < 4; ++j) acc[i][j] = (f32x4){0.f, 0.f, 0.f, 0.f};

    for (int kb = 0; kb < DIM; kb += BKK) {
      llds16(ag + kb, aL);
      llds16(ag + kb + (16 << 10), aL + 16 * BKK);
      llds16(bg + kb, bL);
      llds16(bg + kb + (16 << 10), bL + 16 * BKK);
      __syncthreads();

      const ushort* abase = sA + (qr + m) * BKK + quad * 8;
      const ushort* bbase = sB + (qch * 64 + m) * BKK + quad * 8;
      short8 af[4], bfr[4];
#pragma unroll
      for (int i = 0; i < 4; ++i) af[i] = *(const short8*)(abase + i * 16 * BKK);
#pragma unroll
      for (int j = 0; j < 4; ++j) bfr[j] = *(const short8*)(bbase + j * 16 * BKK);
#pragma unroll
      for (int i = 0; i < 4; ++i)
#pragma unroll
        for (int j = 0; j < 4; ++j)
          acc[i][j] = __builtin_amdgcn_mfma_f32_16x16x32_bf16(af[i], bfr[j], acc[i][j], 0, 0, 0);
      __syncthreads();
    }

    epilogue_tile(sm, acc, c0, qr, qch, quad, m, tid, topp, thr);
  }

  writeback_partials(sm, topp, tid, r0, chunk, partials);
}

// distinct names: rocprof Kernel_Name reveals the ws_size bracket
__global__ __launch_bounds__(256) void sim_pre_wsA(  // ws >= 313 MB
    const ushort* __restrict__ srcn, const ushort* __restrict__ tgtn,
    u64* __restrict__ partials) { sim_pre_body(srcn, tgtn, partials); }
__global__ __launch_bounds__(256) void sim_pre_wsB(  // ws >= 210 MB
    const ushort* __restrict__ srcn, const ushort* __restrict__ tgtn,
    u64* __restrict__ partials) { sim_pre_body(srcn, tgtn, partials); }
__global__ __launch_bounds__(256) void sim_pre_wsC(  // ws >= 158 MB
    const ushort* __restrict__ srcn, const ushort* __restrict__ tgtn,
    u64* __restrict__ partials) { sim_pre_body(srcn, tgtn, partials); }
__global__ __launch_bounds__(256) void sim_pre_wsD(  // ws >= 113 MB
    const ushort* __restrict__ srcn, const ushort* __restrict__ tgtn,
    u64* __restrict__ partials) { sim_pre_body(srcn, tgtn, partials); }

// ---------------- Kernel 4: parallel merge, fp64 refine, gather+average ----
__global__ __launch_bounds__(256) void merge_gather_kernel(
    const u64* __restrict__ partials, const float* __restrict__ src,
    const float* __restrict__ tgt, float* __restrict__ out) {
  const int row = blockIdx.x;
  const int tid = threadIdx.x;
  const int lane = tid & 63;
  const int wave = tid >> 6;
  __shared__ u64 cbuf[NCAND];
  __shared__ u64 part8[8][REFINE];
  __shared__ int cand[REFINE];
  __shared__ double cval[REFINE];
  __shared__ int fin[KNN];

  for (int c = tid; c < NCAND; c += 256) cbuf[c] = partials[(size_t)row * NCAND + c];
  __syncthreads();

  // stage 1: 8 parallel scanners over 49 candidates each (one wave, lockstep)
  if (tid < 8) {
    u64 t8[REFINE];
#pragma unroll
    for (int j = 0; j < REFINE; ++j) t8[j] = 0;
    const int base = tid * (NCAND / 8);
    for (int c = 0; c < NCAND / 8; ++c) insU<REFINE>(cbuf[base + c], t8);
#pragma unroll
    for (int j = 0; j < REFINE; ++j) part8[tid][j] = t8[j];
  }
  __syncthreads();
  if (tid == 0) {
    u64 t8[REFINE];
#pragma unroll
    for (int j = 0; j < REFINE; ++j) t8[j] = 0;
    for (int s = 0; s < 8; ++s)
#pragma unroll
      for (int j = 0; j < REFINE; ++j) insU<REFINE>(part8[s][j], t8);
#pragma unroll
    for (int j = 0; j < REFINE; ++j) cand[j] = (int)(~(uint)t8[j]);
  }
  __syncthreads();

  // fp64 re-score: one wave per candidate (2 each), shuffle-only reductions
  const float4* s4 = (const float4*)(src + ((size_t)row << 10));
  float4 s0 = s4[lane], s1 = s4[lane + 64], s2 = s4[lane + 128], s3 = s4[lane + 192];
  double ss = (double)s0.x * s0.x + (double)s0.y * s0.y + (double)s0.z * s0.z + (double)s0.w * s0.w
            + (double)s1.x * s1.x + (double)s1.y * s1.y + (double)s1.z * s1.z + (double)s1.w * s1.w
            + (double)s2.x * s2.x + (double)s2.y * s2.y + (double)s2.z * s2.z + (double)s2.w * s2.w
            + (double)s3.x * s3.x + (double)s3.y * s3.y + (double)s3.z * s3.z + (double)s3.w * s3.w;
#pragma unroll
  for (int off = 32; off; off >>= 1) ss += __shfl_down(ss, off, 64);
  ss = __shfl(ss, 0, 64);
  const double sn = fmax(sqrt(ss), 1e-8);

  for (int cc = wave; cc < REFINE; cc += 4) {
    const float4* t4 = (const float4*)(tgt + ((size_t)cand[cc] << 10));
    float4 t0 = t4[lane], t1 = t4[lane + 64], t2 = t4[lane + 128], t3 = t4[lane + 192];
    double dd = (double)s0.x * t0.x + (double)s0.y * t0.y + (double)s0.z * t0.z + (double)s0.w * t0.w
              + (double)s1.x * t1.x + (double)s1.y * t1.y + (double)s1.z * t1.z + (double)s1.w * t1.w
              + (double)s2.x * t2.x + (double)s2.y * t2.y + (double)s2.z * t2.z + (double)s2.w * t2.w
              + (double)s3.x * t3.x + (double)s3.y * t3.y + (double)s3.z * t3.z + (double)s3.w * t3.w;
    double tt = (double)t0.x * t0.x + (double)t0.y * t0.y + (double)t0.z * t0.z + (double)t0.w * t0.w
              + (double)t1.x * t1.x + (double)t1.y * t1.y + (double)t1.z * t1.z + (double)t1.w * t1.w
              + (double)t2.x * t2.x + (double)t2.y * t2.y + (double)t2.z * t2.z + (double)t2.w * t2.w
              + (double)t3.x * t3.x + (double)t3.y * t3.y + (double)t3.z * t3.z + (double)t3.w * t3.w;
#pragma unroll
    for (int off = 32; off; off >>= 1) {
      dd += __shfl_down(dd, off, 64);
      tt += __shfl_down(tt, off, 64);
    }
    if (lane == 0) cval[cc] = dd / (sn * fmax(sqrt(tt), 1e-8));
  }
  __syncthreads();

  if (tid == 0) {
    bool used[REFINE];
#pragma unroll
    for (int j = 0; j < REFINE; ++j) used[j] = false;
    for (int k = 0; k < KNN; ++k) {
      int bj = -1; double bv = 0.0; int bidx = 0x7fffffff;
      for (int j = 0; j < REFINE; ++j) {
        if (used[j]) continue;
        if (bj < 0 || cval[j] > bv || (cval[j] == bv && cand[j] < bidx)) {
          bj = j; bv = cval[j]; bidx = cand[j];
        }
      }
      used[bj] = true;
      fin[k] = cand[bj];
    }
  }
  __syncthreads();

  const int d = tid * 4;
  float4 a = *(const float4*)(tgt + ((size_t)fin[0] << 10) + d);
  float4 b = *(const float4*)(tgt + ((size_t)fin[1] << 10) + d);
  float4 c = *(const float4*)(tgt + ((size_t)fin[2] << 10) + d);
  float4 e = *(const float4*)(tgt + ((size_t)fin[3] << 10) + d);
  float4 o;
  o.x = 0.25f * (a.x + b.x + c.x + e.x);
  o.y = 0.25f * (a.y + b.y + c.y + e.y);
  o.z = 0.25f * (a.z + b.z + c.z + e.z);
  o.w = 0.25f * (a.w + b.w + c.w + e.w);
  *(float4*)(out + ((size_t)row << 10) + d) = o;
}

extern "C" void kernel_launch(void* const* d_in, const int* in_sizes, int n_in,
                              void* d_out, int out_size, void* d_ws, size_t ws_size,
                              hipStream_t stream) {
  const float* src = (const float*)d_in[0];
  const float* tgt = (const float*)d_in[1];
  float* out = (float*)d_out;
  char* ws = (char*)d_ws;

  const size_t SRCN_B = (size_t)S_ROWS * DIM * sizeof(ushort);   // 4.19 MB
  const size_t TGTN_B = (size_t)T_PAD * DIM * sizeof(ushort);    // 102.76 MB
  const size_t PART_B = (size_t)S_ROWS * NCAND * sizeof(u64);    // 6.42 MB
  const size_t SIMS_FULL = (size_t)S_ROWS * T_PAD * 2;           // 205.5 MB

  ushort* srcn = (ushort*)ws;
  ushort* tgtn = (ushort*)(ws + SRCN_B);
  u64* partials = (u64*)(ws + SRCN_B + TGTN_B);

  norm_src_kernel<<<S_ROWS, 256, 0, stream>>>(src, srcn);
  conv_tgt_kernel<<<T_PAD, 256, 0, stream>>>(tgt, tgtn);

  dim3 g3(S_ROWS / BM, NUM_CHUNKS);  // x fastest => row-tiles share a tgt chunk in L2
  // ws probe: identical kernels, distinct names; Kernel_Name reveals the bracket
  if (ws_size >= SRCN_B + TGTN_B + SIMS_FULL + (1 << 20))
    sim_pre_wsA<<<g3, 256, 0, stream>>>(srcn, tgtn, partials);
  else if (ws_size >= SRCN_B + TGTN_B + SIMS_FULL / 2 + (1 << 20))
    sim_pre_wsB<<<g3, 256, 0, stream>>>(srcn, tgtn, partials);
  else if (ws_size >= SRCN_B + TGTN_B + SIMS_FULL / 4 + (1 << 20))
    sim_pre_wsC<<<g3, 256, 0, stream>>>(srcn, tgtn, partials);
  else
    sim_pre_wsD<<<g3, 256, 0, stream>>>(srcn, tgtn, partials);

  merge_gather_kernel<<<S_ROWS, 256, 0, stream>>>(partials, src, tgt, out);
}

// Round 5
// 649.109 us; speedup vs baseline: 6.5905x; 1.2547x over previous
//
#include <hip/hip_runtime.h>
#include <math.h>

#define S_ROWS 2048
#define T_ROWS 50000
#define DIM    1024
#define KNN    4

#define BM 128
#define BN 128
#define KBB 128                                              /* K-slab bytes (=128 i8) */
#define TILES_PER_CHUNK 4
#define CHUNK_COLS (BN * TILES_PER_CHUNK)                    /* 512   */
#define NUM_CHUNKS ((T_ROWS + CHUNK_COLS - 1) / CHUNK_COLS)  /* 98    */
#define T_PAD (NUM_CHUNKS * CHUNK_COLS)                      /* 50176 */
#define NCAND (NUM_CHUNKS * KNN)                             /* 392   */
#define REFINE 16
#define SP 67  /* sims LDS row stride (ints): odd => conflict-free b32 scan */
#define QSCALE 500.0f

typedef unsigned int uint;
typedef unsigned long long u64;
typedef signed char i8;
typedef __attribute__((ext_vector_type(4))) int i32x4;

// order-preserving pack for signed-i32 sims: key high 32, ~idx low 32
// (lower idx wins exact ties, matching jax.lax.top_k)
__device__ __forceinline__ u64 packI(int v, int idx) {
  return ((u64)((uint)v ^ 0x80000000u) << 32) | (uint)(~idx);
}

template <int N>
__device__ __forceinline__ void insU(u64 p, u64 (&tv)[N]) {
  if (p <= tv[N - 1]) return;
  tv[N - 1] = p;
#pragma unroll
  for (int j = N - 1; j > 0; --j) {
    if (tv[j] > tv[j - 1]) { u64 t = tv[j]; tv[j] = tv[j - 1]; tv[j - 1] = t; }
  }
}

// async global->LDS, 16 B/lane (global_load_lds_dwordx4); dest = wave-uniform
// base + lane*16 (m104/m108) — we pick each lane's global source to implement
// the XOR bank-swizzle.
__device__ __forceinline__ void llds16(const void* g, void* l) {
  __builtin_amdgcn_global_load_lds(
      reinterpret_cast<__attribute__((address_space(1))) void*>(
          reinterpret_cast<uintptr_t>(g)),
      reinterpret_cast<__attribute__((address_space(3))) void*>(
          (unsigned)reinterpret_cast<uintptr_t>(l)),
      16, 0, 0);
}

__device__ __forceinline__ int imax2(int a, int b) { return a > b ? a : b; }

// ---- Kernel 1: normalize rows, quantize to i8 (scale 500), pad with zeros ----
__global__ __launch_bounds__(256) void quant_kernel(const float* __restrict__ in,
                                                    i8* __restrict__ outq, int nvalid) {
  const int row = blockIdx.x;
  const int tid = threadIdx.x;
  if (row >= nvalid) {  // pad rows: zeros => sims 0; scan guards g<T_ROWS anyway
    ((uint*)(outq + ((size_t)row << 10)))[tid] = 0u;
    return;
  }
  __shared__ float red[4];
  float4 v = ((const float4*)(in + ((size_t)row << 10)))[tid];
  float s = v.x * v.x + v.y * v.y + v.z * v.z + v.w * v.w;
#pragma unroll
  for (int off = 32; off; off >>= 1) s += __shfl_down(s, off, 64);
  if ((tid & 63) == 0) red[tid >> 6] = s;
  __syncthreads();
  float tot = red[0] + red[1] + red[2] + red[3];
  float r = QSCALE / fmaxf(sqrtf(tot), 1e-8f);
  int q0 = __float2int_rn(v.x * r), q1 = __float2int_rn(v.y * r);
  int q2 = __float2int_rn(v.z * r), q3 = __float2int_rn(v.w * r);
  q0 = imax2(-127, (q0 < 127 ? q0 : 127));
  q1 = imax2(-127, (q1 < 127 ? q1 : 127));
  q2 = imax2(-127, (q2 < 127 ? q2 : 127));
  q3 = imax2(-127, (q3 < 127 ? q3 : 127));
  uint packed = ((uint)q0 & 255u) | (((uint)q1 & 255u) << 8) |
                (((uint)q2 & 255u) << 16) | (((uint)q3 & 255u) << 24);
  ((uint*)(outq + ((size_t)row << 10)))[tid] = packed;
}

// ---------------- sim kernel: i8 MFMA GEMM + fused per-chunk top-4 ----------
union __align__(16) SimSmem {
  i8 ab[2][BM * KBB];  // sA, sB: 16 KB each
  int sims[BM * SP];   // 34304 B (max member)
  u64 mb[256 * KNN];   // 8 KB merge buffer
};

__global__ __launch_bounds__(256) void sim_i8_kernel(const i8* __restrict__ srcq,
                                                     const i8* __restrict__ tgtq,
                                                     u64* __restrict__ partials) {
  __shared__ SimSmem sm;
  i8* sA = sm.ab[0];
  i8* sB = sm.ab[1];

  const int tid = threadIdx.x;
  const int lane = tid & 63;
  const int wave = tid >> 6;
  const int qr = (wave >> 1) * 64;  // quadrant row base
  const int qch = wave & 1;         // quadrant col half
  const int m = lane & 15;
  const int quad = lane >> 4;
  const int r0 = blockIdx.x * BM;
  const int chunk = blockIdx.y;

  // staging lane map: DMA d covers rows [wave*32+d*8, +8); lane i holds
  // (row = base + (i>>3), stored block i&7) containing global block
  // (i&7)^(i>>3)  — the XOR swizzle that makes frag reads 2-way (free).
  const int srow8 = lane >> 3;
  const int scb = (lane & 7) ^ srow8;
  const i8* aBase = srcq + (((size_t)(r0 + wave * 32 + srow8)) << 10) + scb * 16;
  i8* aL = sA + wave * 4096;
  i8* bL = sB + wave * 4096;

  // frag read offsets: logical block q lives at stored position q^(row&7);
  // row&7 == m&7 for all frag rows (row = base16k + m, base16k % 16 == 0)
  const int axor = m & 7;
  const int aoff = (qr + m) * KBB;
  const int boff = (qch * 64 + m) * KBB;

  u64 topp[KNN] = {0, 0, 0, 0};
  int thrI = (int)0x80000000;  // INT_MIN

  for (int tile = 0; tile < TILES_PER_CHUNK; ++tile) {
    const int c0 = chunk * CHUNK_COLS + tile * BN;
    const i8* bBase = tgtq + (((size_t)(c0 + wave * 32 + srow8)) << 10) + scb * 16;

    i32x4 acc[4][4];
#pragma unroll
    for (int i = 0; i < 4; ++i)
#pragma unroll
      for (int j = 0; j < 4; ++j) acc[i][j] = (i32x4){0, 0, 0, 0};

    for (int kb = 0; kb < DIM; kb += KBB) {  // 8 iters (i8: 1 B/elem)
#pragma unroll
      for (int d = 0; d < 4; ++d) {
        llds16(aBase + kb + d * 8192, aL + d * 1024);
        llds16(bBase + kb + d * 8192, bL + d * 1024);
      }
      __syncthreads();
#pragma unroll
      for (int s = 0; s < 2; ++s) {  // two K=64 MFMA steps per slab
        const int bpos = ((s * 4 + quad) ^ axor) * 16;
        i32x4 af[4], bf[4];
#pragma unroll
        for (int i = 0; i < 4; ++i)
          af[i] = *(const i32x4*)(sA + aoff + i * (16 * KBB) + bpos);
#pragma unroll
        for (int j = 0; j < 4; ++j)
          bf[j] = *(const i32x4*)(sB + boff + j * (16 * KBB) + bpos);
#pragma unroll
        for (int i = 0; i < 4; ++i)
#pragma unroll
          for (int j = 0; j < 4; ++j)
            acc[i][j] = __builtin_amdgcn_mfma_i32_16x16x64_i8(af[i], bf[j], acc[i][j], 0, 0, 0);
      }
      __syncthreads();
    }

    // epilogue: C layout row=(lane>>4)*4+reg, col=lane&15 (shape-determined,
    // dtype-independent — m121/m127/m128). Two 64-col phases through LDS.
#pragma unroll
    for (int ph = 0; ph < 2; ++ph) {
      if (qch == ph) {
#pragma unroll
        for (int i = 0; i < 4; ++i)
#pragma unroll
          for (int j = 0; j < 4; ++j)
#pragma unroll
            for (int reg = 0; reg < 4; ++reg)
              sm.sims[(qr + i * 16 + quad * 4 + reg) * SP + j * 16 + m] = acc[i][j][reg];
      }
      __syncthreads();
      {
        const int rowl = tid & 127;
        const int chh = tid >> 7;
        const int* srow = &sm.sims[rowl * SP + chh * 32];
        const int gbase = c0 + ph * 64 + chh * 32;
#pragma unroll
        for (int c = 0; c < 32; c += 4) {
          int a = srow[c], b = srow[c + 1], d2 = srow[c + 2], e = srow[c + 3];
          int mx = imax2(imax2(a, b), imax2(d2, e));
          if (mx > thrI) {  // rare
            const int g = gbase + c;
            if (g + 0 < T_ROWS) insU<KNN>(packI(a, g + 0), topp);
            if (g + 1 < T_ROWS) insU<KNN>(packI(b, g + 1), topp);
            if (g + 2 < T_ROWS) insU<KNN>(packI(d2, g + 2), topp);
            if (g + 3 < T_ROWS) insU<KNN>(packI(e, g + 3), topp);
            thrI = (int)((uint)(topp[KNN - 1] >> 32) ^ 0x80000000u);
          }
        }
      }
      __syncthreads();
    }
  }

  // merge the two col-half owners of each row, write chunk partials
#pragma unroll
  for (int j = 0; j < KNN; ++j) sm.mb[tid * KNN + j] = topp[j];
  __syncthreads();
  if (tid < 128) {
#pragma unroll
    for (int j = 0; j < KNN; ++j) insU<KNN>(sm.mb[(tid + 128) * KNN + j], topp);
    u64* dst = partials + ((size_t)(r0 + tid) * NUM_CHUNKS + chunk) * KNN;
#pragma unroll
    for (int j = 0; j < KNN; ++j) dst[j] = topp[j];
  }
}

// ------- Kernel 3: merge partials -> top-16, fp64 refine, gather+average -----
__global__ __launch_bounds__(256) void merge_gather_kernel(
    const u64* __restrict__ partials, const float* __restrict__ src,
    const float* __restrict__ tgt, float* __restrict__ out) {
  const int row = blockIdx.x;
  const int tid = threadIdx.x;
  const int lane = tid & 63;
  const int wave = tid >> 6;
  __shared__ u64 cbuf[NCAND];
  __shared__ u64 part8[8][REFINE];
  __shared__ int cand[REFINE];
  __shared__ double cval[REFINE];
  __shared__ int fin[KNN];

  for (int c = tid; c < NCAND; c += 256) cbuf[c] = partials[(size_t)row * NCAND + c];
  __syncthreads();

  // stage 1: 8 parallel scanners (one wave, lockstep), top-16 each
  if (tid < 8) {
    u64 t16[REFINE];
#pragma unroll
    for (int j = 0; j < REFINE; ++j) t16[j] = 0;
    const int base = tid * (NCAND / 8);
    for (int c = 0; c < NCAND / 8; ++c) insU<REFINE>(cbuf[base + c], t16);
#pragma unroll
    for (int j = 0; j < REFINE; ++j) part8[tid][j] = t16[j];
  }
  __syncthreads();
  if (tid == 0) {
    u64 t16[REFINE];
#pragma unroll
    for (int j = 0; j < REFINE; ++j) t16[j] = 0;
    for (int s = 0; s < 8; ++s)
#pragma unroll
      for (int j = 0; j < REFINE; ++j) insU<REFINE>(part8[s][j], t16);
#pragma unroll
    for (int j = 0; j < REFINE; ++j) cand[j] = (int)(~(uint)t16[j]);
  }
  __syncthreads();

  // fp64 re-score of the 16 candidates: pins selection to the true fp ordering
  const float4* s4 = (const float4*)(src + ((size_t)row << 10));
  float4 s0 = s4[lane], s1 = s4[lane + 64], s2 = s4[lane + 128], s3 = s4[lane + 192];
  double ss = (double)s0.x * s0.x + (double)s0.y * s0.y + (double)s0.z * s0.z + (double)s0.w * s0.w
            + (double)s1.x * s1.x + (double)s1.y * s1.y + (double)s1.z * s1.z + (double)s1.w * s1.w
            + (double)s2.x * s2.x + (double)s2.y * s2.y + (double)s2.z * s2.z + (double)s2.w * s2.w
            + (double)s3.x * s3.x + (double)s3.y * s3.y + (double)s3.z * s3.z + (double)s3.w * s3.w;
#pragma unroll
  for (int off = 32; off; off >>= 1) ss += __shfl_down(ss, off, 64);
  ss = __shfl(ss, 0, 64);
  const double sn = fmax(sqrt(ss), 1e-8);

  for (int cc = wave; cc < REFINE; cc += 4) {
    const float4* t4 = (const float4*)(tgt + ((size_t)cand[cc] << 10));
    float4 t0 = t4[lane], t1 = t4[lane + 64], t2 = t4[lane + 128], t3 = t4[lane + 192];
    double dd = (double)s0.x * t0.x + (double)s0.y * t0.y + (double)s0.z * t0.z + (double)s0.w * t0.w
              + (double)s1.x * t1.x + (double)s1.y * t1.y + (double)s1.z * t1.z + (double)s1.w * t1.w
              + (double)s2.x * t2.x + (double)s2.y * t2.y + (double)s2.z * t2.z + (double)s2.w * t2.w
              + (double)s3.x * t3.x + (double)s3.y * t3.y + (double)s3.z * t3.z + (double)s3.w * t3.w;
    double tt = (double)t0.x * t0.x + (double)t0.y * t0.y + (double)t0.z * t0.z + (double)t0.w * t0.w
              + (double)t1.x * t1.x + (double)t1.y * t1.y + (double)t1.z * t1.z + (double)t1.w * t1.w
              + (double)t2.x * t2.x + (double)t2.y * t2.y + (double)t2.z * t2.z + (double)t2.w * t2.w
              + (double)t3.x * t3.x + (double)t3.y * t3.y + (double)t3.z * t3.z + (double)t3.w * t3.w;
#pragma unroll
    for (int off = 32; off; off >>= 1) {
      dd += __shfl_down(dd, off, 64);
      tt += __shfl_down(tt, off, 64);
    }
    if (lane == 0) cval[cc] = dd / (sn * fmax(sqrt(tt), 1e-8));
  }
  __syncthreads();

  if (tid == 0) {
    bool used[REFINE];
#pragma unroll
    for (int j = 0; j < REFINE; ++j) used[j] = false;
    for (int k = 0; k < KNN; ++k) {
      int bj = -1; double bv = 0.0; int bidx = 0x7fffffff;
      for (int j = 0; j < REFINE; ++j) {
        if (used[j]) continue;
        if (bj < 0 || cval[j] > bv || (cval[j] == bv && cand[j] < bidx)) {
          bj = j; bv = cval[j]; bidx = cand[j];
        }
      }
      used[bj] = true;
      fin[k] = cand[bj];
    }
  }
  __syncthreads();

  const int d = tid * 4;
  float4 a = *(const float4*)(tgt + ((size_t)fin[0] << 10) + d);
  float4 b = *(const float4*)(tgt + ((size_t)fin[1] << 10) + d);
  float4 c = *(const float4*)(tgt + ((size_t)fin[2] << 10) + d);
  float4 e = *(const float4*)(tgt + ((size_t)fin[3] << 10) + d);
  float4 o;
  o.x = 0.25f * (a.x + b.x + c.x + e.x);
  o.y = 0.25f * (a.y + b.y + c.y + e.y);
  o.z = 0.25f * (a.z + b.z + c.z + e.z);
  o.w = 0.25f * (a.w + b.w + c.w + e.w);
  *(float4*)(out + ((size_t)row << 10) + d) = o;
}

extern "C" void kernel_launch(void* const* d_in, const int* in_sizes, int n_in,
                              void* d_out, int out_size, void* d_ws, size_t ws_size,
                              hipStream_t stream) {
  const float* src = (const float*)d_in[0];
  const float* tgt = (const float*)d_in[1];
  float* out = (float*)d_out;
  char* ws = (char*)d_ws;

  const size_t SRCQ_B = (size_t)S_ROWS << 10;  // 2.10 MB (i8)
  const size_t TGTQ_B = (size_t)T_PAD << 10;   // 51.38 MB (i8)

  i8* srcq = (i8*)ws;
  i8* tgtq = (i8*)(ws + SRCQ_B);
  u64* partials = (u64*)(ws + SRCQ_B + TGTQ_B);  // 6.42 MB; total < 60 MB (ws >= 313 MB proven)

  quant_kernel<<<S_ROWS, 256, 0, stream>>>(src, srcq, S_ROWS);
  quant_kernel<<<T_PAD, 256, 0, stream>>>(tgt, tgtq, T_ROWS);

  dim3 g3(S_ROWS / BM, NUM_CHUNKS);  // x fastest => row-tiles share a tgt chunk in L2
  sim_i8_kernel<<<g3, 256, 0, stream>>>(srcq, tgtq, partials);

  merge_gather_kernel<<<S_ROWS, 256, 0, stream>>>(partials, src, tgt, out);
}